// Round 10
// baseline (206.391 us; speedup 1.0000x reference)
//
#include <hip/hip_runtime.h>

typedef unsigned short u16;
typedef unsigned int u32;
typedef __attribute__((ext_vector_type(8))) short bf16x8;
typedef __attribute__((ext_vector_type(4))) float f32x4;
typedef __attribute__((ext_vector_type(4))) u32 u32x4;

union U8 { u32 w[4]; u32x4 u4; bf16x8 v; };

#define LEAKY 0.2f
#define LN_EPS 1e-5f

// fp32 -> bf16 RTNE (bit math — proven; v_cvt_pk asm poisons words, round 6)
__device__ __forceinline__ u16 f2bf(float f) {
  union { float f; u32 u; } a; a.f = f;
  return (u16)((a.u + 0x7fffu + ((a.u >> 16) & 1u)) >> 16);
}
__device__ __forceinline__ u32 pk2(float lo, float hi) {
  return (u32)f2bf(lo) | ((u32)f2bf(hi) << 16);
}
__device__ __forceinline__ u32x4 pack8(const f32x4& a, const f32x4& b) {
  u32x4 r;
  r[0] = pk2(a[0], a[1]); r[1] = pk2(a[2], a[3]);
  r[2] = pk2(b[0], b[1]); r[3] = pk2(b[2], b[3]);
  return r;
}

// Build 128KB weight fragment image (128 frags x 1KB). frag f: lane l holds 8
// contiguous bf16 (one conflict-free ds_read_b128 at f*1024 + l*16).
// f = base + c*8 + n; W1: f 0..63 (c 0..3 = W1a/dest, c 4..7 = W1b/src);
// W2: f 64..95; W3: f 96..127.
// Element (f,l,i): p=l&15, q=l>>4, j=i&3, h=i>>2 -> W[16n+p][32c+4q+j+16h]
__global__ void build_wfrag(const float* __restrict__ W1,
                            const float* __restrict__ W2,
                            const float* __restrict__ W3,
                            u16* __restrict__ wout) {
  int id = blockIdx.x * 256 + threadIdx.x;     // 0..65535
  int f = id >> 9, l = (id >> 3) & 63, i = id & 7;
  int p = l & 15, q = l >> 4, j = i & 3, h = i >> 2;
  const float* W; int c, K;
  if (f < 64)      { W = W1; c = f >> 3;        K = 256; }
  else if (f < 96) { W = W2; c = (f - 64) >> 3; K = 128; }
  else             { W = W3; c = (f - 96) >> 3; K = 128; }
  int n = f & 7;
  wout[id] = f2bf(W[(16 * n + p) * K + 32 * c + 4 * q + j + 16 * h]);
}

// single-tile layer (M=16): frag f = FBASE + c*8 + n, one MFMA per frag read
template <int FBASE>
__device__ __forceinline__ void gemm16(const u16* __restrict__ wlds, int lane,
                                       const U8* mf, f32x4* acc) {
  #pragma unroll
  for (int c = 0; c < 4; ++c) {
    #pragma unroll
    for (int n = 0; n < 8; ++n) {
      U8 wf;
      wf.v = *(const bf16x8*)(wlds + ((FBASE + c * 8 + n) << 9) + (lane << 3));
      acc[n] = __builtin_amdgcn_mfma_f32_16x16x32_bf16(wf.v, mf[c].v, acc[n], 0, 0, 0);
    }
  }
}

// leaky (= max(v, 0.2v)) in place, then pack to next layer's bf16 frags
__device__ __forceinline__ void leaky_pack(f32x4* acc, U8* hf) {
  #pragma unroll
  for (int n = 0; n < 8; ++n) {
    #pragma unroll
    for (int j = 0; j < 4; ++j) {
      float v = acc[n][j];
      acc[n][j] = fmaxf(v, LEAKY * v);
    }
  }
  #pragma unroll
  for (int c = 0; c < 4; ++c) hf[c].u4 = pack8(acc[2 * c], acc[2 * c + 1]);
}

// h1 frag word: leaky(bf16(ya)+bf16(yb)) on a packed pair
__device__ __forceinline__ u32 addleaky(u32 ua, u32 ub) {
  float alo = __uint_as_float(ua << 16);
  float ahi = __uint_as_float(ua & 0xFFFF0000u);
  float blo = __uint_as_float(ub << 16);
  float bhi = __uint_as_float(ub & 0xFFFF0000u);
  float lo = alo + blo, hi = ahi + bhi;
  lo = fmaxf(lo, LEAKY * lo);
  hi = fmaxf(hi, LEAKY * hi);
  return pk2(lo, hi);
}

// LayerNorm one 16-edge tile: acc[n][j] = h[edge p][chan 16n+4q+j].
// SCALAR stores (round-1/9 proven: WRITE_SIZE == output bytes; vector f32x4
// stores correlated with write amplification in rounds 5-8).
__device__ __forceinline__ void ln_store(const f32x4* acc, const f32x4* gmf,
                                         const f32x4* btf, int q,
                                         float* __restrict__ orow) {
  float s = 0.f, ss = 0.f;
  #pragma unroll
  for (int n = 0; n < 8; ++n) {
    #pragma unroll
    for (int j = 0; j < 4; ++j) { float v = acc[n][j]; s += v; ss += v * v; }
  }
  s += __shfl_xor(s, 16, 64);  ss += __shfl_xor(ss, 16, 64);
  s += __shfl_xor(s, 32, 64);  ss += __shfl_xor(ss, 32, 64);
  float mean = s * (1.f / 128.f);
  float var  = fmaxf(ss * (1.f / 128.f) - mean * mean, 0.f);
  float inv  = rsqrtf(var + LN_EPS);
  #pragma unroll
  for (int n = 0; n < 8; ++n) {
    f32x4 gm = gmf[4 * n + q], bt = btf[4 * n + q];
    #pragma unroll
    for (int j = 0; j < 4; ++j)
      orow[16 * n + j] = (acc[n][j] - mean) * inv * gm[j] + bt[j];
  }
}

// ---- node precompute: y[n] = [ bf16(x[n]@W1a^T) | bf16(x[n]@W1b^T + b1) ]
// fragment order: elem (c, q, i=j+4h) at u16 offset c*32 + q*8 + i
__global__ __launch_bounds__(512, 2) void node_pre(
    const float* __restrict__ x, const float* __restrict__ b1,
    const u16* __restrict__ wbf, u16* __restrict__ y, int NN) {
  __shared__ __align__(16) u16 wlds[32768];   // W1 frags (0..63), 64KB
  __shared__ __align__(16) float b1l[128];
  const int tid = threadIdx.x;
  {
    const uint4* s = (const uint4*)wbf;
    uint4* d = (uint4*)wlds;
    #pragma unroll
    for (int i = 0; i < 8; ++i) d[tid + i * 512] = s[tid + i * 512];
  }
  if (tid < 128) b1l[tid] = b1[tid];
  __syncthreads();

  const int lane = tid & 63, p = lane & 15, q = lane >> 4;
  const int wid = (blockIdx.x << 3) | (tid >> 6);
  const f32x4* b1f = (const f32x4*)b1l;
  const int NT = (NN + 15) >> 4;   // 16 nodes per wave-tile

  for (int t = wid; t < NT; t += 2048) {
    const int r = t * 16 + p;
    const int cr = r < NN ? r : NN - 1;
    U8 mf[4];
    #pragma unroll
    for (int c = 0; c < 4; ++c) {
      float4 a0 = *(const float4*)(x + (long)cr * 128 + 32 * c + 4 * q);
      float4 a1 = *(const float4*)(x + (long)cr * 128 + 32 * c + 4 * q + 16);
      mf[c].w[0] = pk2(a0.x, a0.y); mf[c].w[1] = pk2(a0.z, a0.w);
      mf[c].w[2] = pk2(a1.x, a1.y); mf[c].w[3] = pk2(a1.z, a1.w);
    }
    f32x4 ya[8], yb[8];
    #pragma unroll
    for (int n = 0; n < 8; ++n) {
      ya[n] = (f32x4)(0.f);
      yb[n] = b1f[4 * n + q];
    }
    gemm16<0>(wlds, lane, mf, ya);    // W1a (dest part)
    gemm16<32>(wlds, lane, mf, yb);   // W1b (src part, +b1)
    #pragma unroll
    for (int c = 0; c < 4; ++c) {
      *(u32x4*)(y + (long)r * 256 + c * 32 + q * 8)       = pack8(ya[2*c], ya[2*c+1]);
      *(u32x4*)(y + (long)r * 256 + 128 + c * 32 + q * 8) = pack8(yb[2*c], yb[2*c+1]);
    }
  }
}

// ---- edge kernel: NON-persistent dispatch-order blocks. Block = 1024
// contiguous edges; wave = 128 edges as 8 x 16-edge tiles, 2-deep ping-pong.
// Prologue is gather-FIRST (T14): idx + first two y-gathers issued before the
// weight-staging copy; one barrier drains both -> gather latency hides under
// staging instead of serializing after it (round-9's serial prologue was
// ~20-25% of tile time at 4 tiles/wave).
__global__ __launch_bounds__(512, 2) void edge_mlp_fac(
    const int* __restrict__ ei, const float* __restrict__ b2,
    const float* __restrict__ gamma, const float* __restrict__ beta,
    const u16* __restrict__ wbf, const u16* __restrict__ y,
    float* __restrict__ out, int E) {
  __shared__ __align__(16) u16 wlds[32768];   // W2|W3 frags, 64KB
  __shared__ __align__(16) float parl[384];   // b2 | gamma | beta
  const int tid = threadIdx.x;
  const int lane = tid & 63, p = lane & 15, q = lane >> 4;
  const f32x4* pf = (const f32x4*)parl;   // b2: pf[0..31], gm: +32, bt: +64
  const long ebase = (long)blockIdx.x * 1024 + (tid >> 6) * 128;

#define LOADY(A, B, node_d, node_s)                                   \
  { const u16* yd_ = y + (long)(node_d) * 256;                        \
    const u16* ys_ = y + (long)(node_s) * 256 + 128;                  \
    _Pragma("unroll")                                                 \
    for (int c = 0; c < 4; ++c) {                                     \
      A[c] = *(const u32x4*)(yd_ + c * 32 + q * 8);                   \
      B[c] = *(const u32x4*)(ys_ + c * 32 + q * 8);                   \
    } }

  // -- prologue: gathers first --
  int ndA = ei[E + ebase + p],      nsA = ei[ebase + p];
  int ndB = ei[E + ebase + 16 + p], nsB = ei[ebase + 16 + p];
  u32x4 a0[4], b0[4], a1[4], b1[4];
  LOADY(a0, b0, ndA, nsA);               // tile 0
  LOADY(a1, b1, ndB, nsB);               // tile 1
  ndA = ei[E + ebase + 32 + p]; nsA = ei[ebase + 32 + p];   // t2 idx
  ndB = ei[E + ebase + 48 + p]; nsB = ei[ebase + 48 + p];   // t3 idx

  // -- weight + param staging (overlaps the in-flight gathers) --
  {
    const uint4* s = (const uint4*)wbf;
    uint4* d = (uint4*)wlds;
    #pragma unroll
    for (int i = 0; i < 8; ++i) d[tid + i * 512] = s[tid + i * 512];
  }
  if (tid < 384) {
    int prm = tid >> 7, idx = tid & 127;
    const float* src = (prm == 0) ? b2 : (prm == 1) ? gamma : beta;
    parl[tid] = src[idx];
  }
  __syncthreads();   // drains staging AND gathers together

  auto compute_store = [&](const u32x4* ya, const u32x4* yb, int i) {
    U8 hf[4];
    #pragma unroll
    for (int c = 0; c < 4; ++c) {
      #pragma unroll
      for (int w2 = 0; w2 < 4; ++w2) hf[c].w[w2] = addleaky(ya[c][w2], yb[c][w2]);
    }
    f32x4 acc[8];
    #pragma unroll
    for (int n = 0; n < 8; ++n) acc[n] = pf[4 * n + q];   // GEMM2 init = b2
    gemm16<0>(wlds, lane, hf, acc);
    leaky_pack(acc, hf);
    #pragma unroll
    for (int n = 0; n < 8; ++n) acc[n] = (f32x4)(0.f);    // GEMM3, no bias
    gemm16<32>(wlds, lane, hf, acc);
    ln_store(acc, pf + 32, pf + 64, q,
             out + (ebase + i * 16 + p) * 128 + 4 * q);
  };

  // -- 8 tiles, 2-deep ping-pong; idx rotates 2 pairs (keeps regs <= 128) --
  compute_store(a0, b0, 0);
  LOADY(a0, b0, ndA, nsA);                                  // t2
  ndA = ei[E + ebase + 64 + p]; nsA = ei[ebase + 64 + p];   // t4 idx
  compute_store(a1, b1, 1);
  LOADY(a1, b1, ndB, nsB);                                  // t3
  ndB = ei[E + ebase + 80 + p]; nsB = ei[ebase + 80 + p];   // t5 idx
  compute_store(a0, b0, 2);
  LOADY(a0, b0, ndA, nsA);                                  // t4
  ndA = ei[E + ebase + 96 + p]; nsA = ei[ebase + 96 + p];   // t6 idx
  compute_store(a1, b1, 3);
  LOADY(a1, b1, ndB, nsB);                                  // t5
  ndB = ei[E + ebase + 112 + p]; nsB = ei[ebase + 112 + p]; // t7 idx
  compute_store(a0, b0, 4);
  LOADY(a0, b0, ndA, nsA);                                  // t6
  compute_store(a1, b1, 5);
  LOADY(a1, b1, ndB, nsB);                                  // t7
  compute_store(a0, b0, 6);
  compute_store(a1, b1, 7);
#undef LOADY
}

// ---- fallback (ws too small or E%1024!=0): monolithic M=16 over x ----
__global__ __launch_bounds__(512, 2) void edge_mlp_mono(
    const float* __restrict__ x, const int* __restrict__ ei,
    const float* __restrict__ b1, const float* __restrict__ b2,
    const float* __restrict__ gamma, const float* __restrict__ beta,
    const u16* __restrict__ wbf, float* __restrict__ out, int E) {
  __shared__ __align__(16) u16 wlds[65536];
  __shared__ __align__(16) float parl[512];
  const int tid = threadIdx.x;
  {
    const uint4* s = (const uint4*)wbf;
    uint4* d = (uint4*)wlds;
    #pragma unroll
    for (int i = 0; i < 16; ++i) d[tid + i * 512] = s[tid + i * 512];
  }
  if (tid < 512) {
    int prm = tid >> 7, idx = tid & 127;
    const float* src = (prm == 0) ? b1 : (prm == 1) ? b2 : (prm == 2) ? gamma : beta;
    parl[tid] = src[idx];
  }
  __syncthreads();

  const int lane = tid & 63, p = lane & 15, q = lane >> 4;
  const int wid = (blockIdx.x << 3) | (tid >> 6);
  const f32x4* pf = (const f32x4*)parl;
  const int NT = (E + 15) >> 4;

  for (int t = wid; t < NT; t += 2048) {
    const int e0 = t * 16;
    const int e = (e0 + p < E) ? e0 + p : E - 1;
    const int nd = ei[E + e], ns = ei[e];
    U8 mf[4];
    f32x4 acc[8];
    #pragma unroll
    for (int n = 0; n < 8; ++n) acc[n] = pf[4 * n + q];
    #pragma unroll
    for (int c = 0; c < 4; ++c) {
      float4 a0 = *(const float4*)(x + (long)nd * 128 + 32 * c + 4 * q);
      float4 a1 = *(const float4*)(x + (long)nd * 128 + 32 * c + 4 * q + 16);
      mf[c].w[0] = pk2(a0.x, a0.y); mf[c].w[1] = pk2(a0.z, a0.w);
      mf[c].w[2] = pk2(a1.x, a1.y); mf[c].w[3] = pk2(a1.z, a1.w);
    }
    gemm16<0>(wlds, lane, mf, acc);
    #pragma unroll
    for (int c = 0; c < 4; ++c) {
      float4 a0 = *(const float4*)(x + (long)ns * 128 + 32 * c + 4 * q);
      float4 a1 = *(const float4*)(x + (long)ns * 128 + 32 * c + 4 * q + 16);
      mf[c].w[0] = pk2(a0.x, a0.y); mf[c].w[1] = pk2(a0.z, a0.w);
      mf[c].w[2] = pk2(a1.x, a1.y); mf[c].w[3] = pk2(a1.z, a1.w);
    }
    gemm16<32>(wlds, lane, mf, acc);
    U8 hf[4];
    leaky_pack(acc, hf);
    #pragma unroll
    for (int n = 0; n < 8; ++n) acc[n] = pf[32 + 4 * n + q];
    gemm16<64>(wlds, lane, hf, acc);
    leaky_pack(acc, hf);
    #pragma unroll
    for (int n = 0; n < 8; ++n) acc[n] = (f32x4)(0.f);
    gemm16<96>(wlds, lane, hf, acc);
    if (e0 + p < E)
      ln_store(acc, pf + 64, pf + 96, q, out + (long)(e0 + p) * 128 + 4 * q);
  }
}

extern "C" void kernel_launch(void* const* d_in, const int* in_sizes, int n_in,
                              void* d_out, int out_size, void* d_ws, size_t ws_size,
                              hipStream_t stream) {
  const float* x     = (const float*)d_in[0];
  const int*   ei    = (const int*)d_in[1];
  const float* W1    = (const float*)d_in[2];
  const float* b1    = (const float*)d_in[3];
  const float* W2    = (const float*)d_in[4];
  const float* b2    = (const float*)d_in[5];
  const float* W3    = (const float*)d_in[6];
  const float* gamma = (const float*)d_in[7];
  const float* beta  = (const float*)d_in[8];
  const int E  = in_sizes[1] / 2;     // 640000
  const int NN = in_sizes[0] / 128;   // 50000

  const size_t npad    = ((size_t)(NN + 31) / 32) * 32;
  const size_t Y_BYTES = npad * 512;             // bf16 ya|yb per node
  const size_t NEED    = Y_BYTES + 131072;

  if (ws_size >= NEED && (E % 1024) == 0) {
    u16* y   = (u16*)d_ws;
    u16* wbf = (u16*)((char*)d_ws + Y_BYTES);
    build_wfrag<<<256, 256, 0, stream>>>(W1, W2, W3, wbf);
    node_pre<<<256, 512, 0, stream>>>(x, b1, wbf, y, NN);
    edge_mlp_fac<<<E / 1024, 512, 0, stream>>>(ei, b2, gamma, beta,
                                               wbf + 32768, y, (float*)d_out, E);
  } else {
    u16* wbf = (u16*)d_ws;
    build_wfrag<<<256, 256, 0, stream>>>(W1, W2, W3, wbf);
    edge_mlp_mono<<<256, 512, 0, stream>>>(x, ei, b1, b2, gamma, beta, wbf,
                                           (float*)d_out, E);
  }
}

// Round 11
// 189.941 us; speedup vs baseline: 1.0866x; 1.0866x over previous
//
#include <hip/hip_runtime.h>

typedef unsigned short u16;
typedef unsigned int u32;
typedef __attribute__((ext_vector_type(8))) short bf16x8;
typedef __attribute__((ext_vector_type(4))) float f32x4;
typedef __attribute__((ext_vector_type(4))) u32 u32x4;

union U8 { u32 w[4]; u32x4 u4; bf16x8 v; };

#define LEAKY 0.2f
#define LN_EPS 1e-5f

// fp32 -> bf16 RTNE (bit math — proven; v_cvt_pk asm poisons words, round 6)
__device__ __forceinline__ u16 f2bf(float f) {
  union { float f; u32 u; } a; a.f = f;
  return (u16)((a.u + 0x7fffu + ((a.u >> 16) & 1u)) >> 16);
}
__device__ __forceinline__ u32 pk2(float lo, float hi) {
  return (u32)f2bf(lo) | ((u32)f2bf(hi) << 16);
}
// TRUNCATING bf16x2 pack in ONE v_perm_b32 (intermediates h1/h2 only; y and
// x->bf16 stay RTNE). D = [hi.b3,hi.b2,lo.b3,lo.b2]; bytes 0-3 = S1, 4-7 = S0.
__device__ __forceinline__ u32 pk2t(float lo, float hi) {
  return __builtin_amdgcn_perm(__float_as_uint(hi), __float_as_uint(lo),
                               0x07060302u);
}
__device__ __forceinline__ u32x4 pack8(const f32x4& a, const f32x4& b) {
  u32x4 r;
  r[0] = pk2(a[0], a[1]); r[1] = pk2(a[2], a[3]);
  r[2] = pk2(b[0], b[1]); r[3] = pk2(b[2], b[3]);
  return r;
}

// Build 128KB weight fragment image (128 frags x 1KB). frag f: lane l holds 8
// contiguous bf16 (one conflict-free ds_read_b128 at f*1024 + l*16).
// f = base + c*8 + n; W1: f 0..63 (c 0..3 = W1a/dest, c 4..7 = W1b/src);
// W2: f 64..95; W3: f 96..127.
// Element (f,l,i): p=l&15, q=l>>4, j=i&3, h=i>>2 -> W[16n+p][32c+4q+j+16h]
__global__ void build_wfrag(const float* __restrict__ W1,
                            const float* __restrict__ W2,
                            const float* __restrict__ W3,
                            u16* __restrict__ wout) {
  int id = blockIdx.x * 256 + threadIdx.x;     // 0..65535
  int f = id >> 9, l = (id >> 3) & 63, i = id & 7;
  int p = l & 15, q = l >> 4, j = i & 3, h = i >> 2;
  const float* W; int c, K;
  if (f < 64)      { W = W1; c = f >> 3;        K = 256; }
  else if (f < 96) { W = W2; c = (f - 64) >> 3; K = 128; }
  else             { W = W3; c = (f - 96) >> 3; K = 128; }
  int n = f & 7;
  wout[id] = f2bf(W[(16 * n + p) * K + 32 * c + 4 * q + j + 16 * h]);
}

// single-tile layer (M=16): frag f = FBASE + c*8 + n, one MFMA per frag read
template <int FBASE>
__device__ __forceinline__ void gemm16(const u16* __restrict__ wlds, int lane,
                                       const U8* mf, f32x4* acc) {
  #pragma unroll
  for (int c = 0; c < 4; ++c) {
    #pragma unroll
    for (int n = 0; n < 8; ++n) {
      U8 wf;
      wf.v = *(const bf16x8*)(wlds + ((FBASE + c * 8 + n) << 9) + (lane << 3));
      acc[n] = __builtin_amdgcn_mfma_f32_16x16x32_bf16(wf.v, mf[c].v, acc[n], 0, 0, 0);
    }
  }
}

// leaky (= max(v, 0.2v)) in place, then pack to next layer's bf16 frags.
// pk2t: 1-op truncating pack (was ~9-op RTNE) — saves ~140 VALU/tile.
__device__ __forceinline__ void leaky_pack(f32x4* acc, U8* hf) {
  #pragma unroll
  for (int n = 0; n < 8; ++n) {
    #pragma unroll
    for (int j = 0; j < 4; ++j) {
      float v = acc[n][j];
      acc[n][j] = fmaxf(v, LEAKY * v);
    }
  }
  #pragma unroll
  for (int c = 0; c < 4; ++c) {
    hf[c].w[0] = pk2t(acc[2 * c][0],     acc[2 * c][1]);
    hf[c].w[1] = pk2t(acc[2 * c][2],     acc[2 * c][3]);
    hf[c].w[2] = pk2t(acc[2 * c + 1][0], acc[2 * c + 1][1]);
    hf[c].w[3] = pk2t(acc[2 * c + 1][2], acc[2 * c + 1][3]);
  }
}

// h1 frag word: leaky(bf16(ya)+bf16(yb)) on a packed pair (truncating pack)
__device__ __forceinline__ u32 addleaky(u32 ua, u32 ub) {
  float alo = __uint_as_float(ua << 16);
  float ahi = __uint_as_float(ua & 0xFFFF0000u);
  float blo = __uint_as_float(ub << 16);
  float bhi = __uint_as_float(ub & 0xFFFF0000u);
  float lo = alo + blo, hi = ahi + bhi;
  lo = fmaxf(lo, LEAKY * lo);
  hi = fmaxf(hi, LEAKY * hi);
  return pk2t(lo, hi);
}

// LayerNorm one 16-edge tile: acc[n][j] = h[edge p][chan 16n+4q+j].
// SCALAR stores (round-1/9 proven: WRITE_SIZE == output bytes; vector f32x4
// stores correlated with write amplification in rounds 5-8).
__device__ __forceinline__ void ln_store(const f32x4* acc, const f32x4* gmf,
                                         const f32x4* btf, int q,
                                         float* __restrict__ orow) {
  float s = 0.f, ss = 0.f;
  #pragma unroll
  for (int n = 0; n < 8; ++n) {
    #pragma unroll
    for (int j = 0; j < 4; ++j) { float v = acc[n][j]; s += v; ss += v * v; }
  }
  s += __shfl_xor(s, 16, 64);  ss += __shfl_xor(ss, 16, 64);
  s += __shfl_xor(s, 32, 64);  ss += __shfl_xor(ss, 32, 64);
  float mean = s * (1.f / 128.f);
  float var  = fmaxf(ss * (1.f / 128.f) - mean * mean, 0.f);
  float inv  = rsqrtf(var + LN_EPS);
  #pragma unroll
  for (int n = 0; n < 8; ++n) {
    f32x4 gm = gmf[4 * n + q], bt = btf[4 * n + q];
    #pragma unroll
    for (int j = 0; j < 4; ++j)
      orow[16 * n + j] = (acc[n][j] - mean) * inv * gm[j] + bt[j];
  }
}

// ---- node precompute: y[n] = [ bf16(x[n]@W1a^T) | bf16(x[n]@W1b^T + b1) ]
// fragment order: elem (c, q, i=j+4h) at u16 offset c*32 + q*8 + i
// (RTNE kept here: y feeds every edge, keep its bias at zero.)
__global__ __launch_bounds__(512, 2) void node_pre(
    const float* __restrict__ x, const float* __restrict__ b1,
    const u16* __restrict__ wbf, u16* __restrict__ y, int NN) {
  __shared__ __align__(16) u16 wlds[32768];   // W1 frags (0..63), 64KB
  __shared__ __align__(16) float b1l[128];
  const int tid = threadIdx.x;
  {
    const uint4* s = (const uint4*)wbf;
    uint4* d = (uint4*)wlds;
    #pragma unroll
    for (int i = 0; i < 8; ++i) d[tid + i * 512] = s[tid + i * 512];
  }
  if (tid < 128) b1l[tid] = b1[tid];
  __syncthreads();

  const int lane = tid & 63, p = lane & 15, q = lane >> 4;
  const int wid = (blockIdx.x << 3) | (tid >> 6);
  const f32x4* b1f = (const f32x4*)b1l;
  const int NT = (NN + 15) >> 4;   // 16 nodes per wave-tile

  for (int t = wid; t < NT; t += 2048) {
    const int r = t * 16 + p;
    const int cr = r < NN ? r : NN - 1;
    U8 mf[4];
    #pragma unroll
    for (int c = 0; c < 4; ++c) {
      float4 a0 = *(const float4*)(x + (long)cr * 128 + 32 * c + 4 * q);
      float4 a1 = *(const float4*)(x + (long)cr * 128 + 32 * c + 4 * q + 16);
      mf[c].w[0] = pk2(a0.x, a0.y); mf[c].w[1] = pk2(a0.z, a0.w);
      mf[c].w[2] = pk2(a1.x, a1.y); mf[c].w[3] = pk2(a1.z, a1.w);
    }
    f32x4 ya[8], yb[8];
    #pragma unroll
    for (int n = 0; n < 8; ++n) {
      ya[n] = (f32x4)(0.f);
      yb[n] = b1f[4 * n + q];
    }
    gemm16<0>(wlds, lane, mf, ya);    // W1a (dest part)
    gemm16<32>(wlds, lane, mf, yb);   // W1b (src part, +b1)
    #pragma unroll
    for (int c = 0; c < 4; ++c) {
      *(u32x4*)(y + (long)r * 256 + c * 32 + q * 8)       = pack8(ya[2*c], ya[2*c+1]);
      *(u32x4*)(y + (long)r * 256 + 128 + c * 32 + q * 8) = pack8(yb[2*c], yb[2*c+1]);
    }
  }
}

// ---- edge kernel: EXACT round-9 schedule (measured 188us total).
// NON-persistent dispatch-order blocks; block = 512 contiguous edges; wave =
// 64 edges as 4 x 16-edge tiles, 2-deep ping-pong pipeline.
__global__ __launch_bounds__(512, 2) void edge_mlp_fac(
    const int* __restrict__ ei, const float* __restrict__ b2,
    const float* __restrict__ gamma, const float* __restrict__ beta,
    const u16* __restrict__ wbf, const u16* __restrict__ y,
    float* __restrict__ out, int E) {
  __shared__ __align__(16) u16 wlds[32768];   // W2|W3 frags, 64KB
  __shared__ __align__(16) float parl[384];   // b2 | gamma | beta
  const int tid = threadIdx.x;
  {
    const uint4* s = (const uint4*)wbf;
    uint4* d = (uint4*)wlds;
    #pragma unroll
    for (int i = 0; i < 8; ++i) d[tid + i * 512] = s[tid + i * 512];
  }
  if (tid < 384) {
    int prm = tid >> 7, idx = tid & 127;
    const float* src = (prm == 0) ? b2 : (prm == 1) ? gamma : beta;
    parl[tid] = src[idx];
  }
  __syncthreads();

  const int lane = tid & 63, p = lane & 15, q = lane >> 4;
  const f32x4* pf = (const f32x4*)parl;   // b2: pf[0..31], gm: +32, bt: +64
  const long ebase = (long)blockIdx.x * 512 + (tid >> 6) * 64;  // wave's 64 edges

  // all 4 tiles' indices up front
  int nd[4], ns[4];
  #pragma unroll
  for (int i = 0; i < 4; ++i) {
    nd[i] = ei[E + ebase + i * 16 + p];
    ns[i] = ei[ebase + i * 16 + p];
  }

#define LOADY(A, B, node_d, node_s)                                   \
  { const u16* yd_ = y + (long)(node_d) * 256;                        \
    const u16* ys_ = y + (long)(node_s) * 256 + 128;                  \
    _Pragma("unroll")                                                 \
    for (int c = 0; c < 4; ++c) {                                     \
      A[c] = *(const u32x4*)(yd_ + c * 32 + q * 8);                   \
      B[c] = *(const u32x4*)(ys_ + c * 32 + q * 8);                   \
    } }

  auto compute_store = [&](const u32x4* ya, const u32x4* yb, int i) {
    U8 hf[4];
    #pragma unroll
    for (int c = 0; c < 4; ++c) {
      #pragma unroll
      for (int w2 = 0; w2 < 4; ++w2) hf[c].w[w2] = addleaky(ya[c][w2], yb[c][w2]);
    }
    f32x4 acc[8];
    #pragma unroll
    for (int n = 0; n < 8; ++n) acc[n] = pf[4 * n + q];   // GEMM2 init = b2
    gemm16<0>(wlds, lane, hf, acc);
    leaky_pack(acc, hf);
    #pragma unroll
    for (int n = 0; n < 8; ++n) acc[n] = (f32x4)(0.f);    // GEMM3, no bias
    gemm16<32>(wlds, lane, hf, acc);
    ln_store(acc, pf + 32, pf + 64, q,
             out + (ebase + i * 16 + p) * 128 + 4 * q);
  };

  // explicit 2-deep ping-pong pipeline (static indexing only — rule #20)
  u32x4 a0[4], b0[4], a1[4], b1[4];
  LOADY(a0, b0, nd[0], ns[0]);
  LOADY(a1, b1, nd[1], ns[1]);
  compute_store(a0, b0, 0);
  LOADY(a0, b0, nd[2], ns[2]);
  compute_store(a1, b1, 1);
  LOADY(a1, b1, nd[3], ns[3]);
  compute_store(a0, b0, 2);
  compute_store(a1, b1, 3);
#undef LOADY
}

// ---- fallback (ws too small or E%512!=0): monolithic M=16 over x ----
__global__ __launch_bounds__(512, 2) void edge_mlp_mono(
    const float* __restrict__ x, const int* __restrict__ ei,
    const float* __restrict__ b1, const float* __restrict__ b2,
    const float* __restrict__ gamma, const float* __restrict__ beta,
    const u16* __restrict__ wbf, float* __restrict__ out, int E) {
  __shared__ __align__(16) u16 wlds[65536];
  __shared__ __align__(16) float parl[512];
  const int tid = threadIdx.x;
  {
    const uint4* s = (const uint4*)wbf;
    uint4* d = (uint4*)wlds;
    #pragma unroll
    for (int i = 0; i < 16; ++i) d[tid + i * 512] = s[tid + i * 512];
  }
  if (tid < 512) {
    int prm = tid >> 7, idx = tid & 127;
    const float* src = (prm == 0) ? b1 : (prm == 1) ? b2 : (prm == 2) ? gamma : beta;
    parl[tid] = src[idx];
  }
  __syncthreads();

  const int lane = tid & 63, p = lane & 15, q = lane >> 4;
  const int wid = (blockIdx.x << 3) | (tid >> 6);
  const f32x4* pf = (const f32x4*)parl;
  const int NT = (E + 15) >> 4;

  for (int t = wid; t < NT; t += 2048) {
    const int e0 = t * 16;
    const int e = (e0 + p < E) ? e0 + p : E - 1;
    const int nd = ei[E + e], ns = ei[e];
    U8 mf[4];
    f32x4 acc[8];
    #pragma unroll
    for (int n = 0; n < 8; ++n) acc[n] = pf[4 * n + q];
    #pragma unroll
    for (int c = 0; c < 4; ++c) {
      float4 a0 = *(const float4*)(x + (long)nd * 128 + 32 * c + 4 * q);
      float4 a1 = *(const float4*)(x + (long)nd * 128 + 32 * c + 4 * q + 16);
      mf[c].w[0] = pk2(a0.x, a0.y); mf[c].w[1] = pk2(a0.z, a0.w);
      mf[c].w[2] = pk2(a1.x, a1.y); mf[c].w[3] = pk2(a1.z, a1.w);
    }
    gemm16<0>(wlds, lane, mf, acc);
    #pragma unroll
    for (int c = 0; c < 4; ++c) {
      float4 a0 = *(const float4*)(x + (long)ns * 128 + 32 * c + 4 * q);
      float4 a1 = *(const float4*)(x + (long)ns * 128 + 32 * c + 4 * q + 16);
      mf[c].w[0] = pk2(a0.x, a0.y); mf[c].w[1] = pk2(a0.z, a0.w);
      mf[c].w[2] = pk2(a1.x, a1.y); mf[c].w[3] = pk2(a1.z, a1.w);
    }
    gemm16<32>(wlds, lane, mf, acc);
    U8 hf[4];
    leaky_pack(acc, hf);
    #pragma unroll
    for (int n = 0; n < 8; ++n) acc[n] = pf[32 + 4 * n + q];
    gemm16<64>(wlds, lane, hf, acc);
    leaky_pack(acc, hf);
    #pragma unroll
    for (int n = 0; n < 8; ++n) acc[n] = (f32x4)(0.f);
    gemm16<96>(wlds, lane, hf, acc);
    if (e0 + p < E)
      ln_store(acc, pf + 64, pf + 96, q, out + (long)(e0 + p) * 128 + 4 * q);
  }
}

extern "C" void kernel_launch(void* const* d_in, const int* in_sizes, int n_in,
                              void* d_out, int out_size, void* d_ws, size_t ws_size,
                              hipStream_t stream) {
  const float* x     = (const float*)d_in[0];
  const int*   ei    = (const int*)d_in[1];
  const float* W1    = (const float*)d_in[2];
  const float* b1    = (const float*)d_in[3];
  const float* W2    = (const float*)d_in[4];
  const float* b2    = (const float*)d_in[5];
  const float* W3    = (const float*)d_in[6];
  const float* gamma = (const float*)d_in[7];
  const float* beta  = (const float*)d_in[8];
  const int E  = in_sizes[1] / 2;     // 640000
  const int NN = in_sizes[0] / 128;   // 50000

  const size_t npad    = ((size_t)(NN + 31) / 32) * 32;
  const size_t Y_BYTES = npad * 512;             // bf16 ya|yb per node
  const size_t NEED    = Y_BYTES + 131072;

  if (ws_size >= NEED && (E % 512) == 0) {
    u16* y   = (u16*)d_ws;
    u16* wbf = (u16*)((char*)d_ws + Y_BYTES);
    build_wfrag<<<256, 256, 0, stream>>>(W1, W2, W3, wbf);
    node_pre<<<256, 512, 0, stream>>>(x, b1, wbf, y, NN);
    edge_mlp_fac<<<E / 512, 512, 0, stream>>>(ei, b2, gamma, beta, wbf + 32768,
                                              y, (float*)d_out, E);
  } else {
    u16* wbf = (u16*)d_ws;
    build_wfrag<<<256, 256, 0, stream>>>(W1, W2, W3, wbf);
    edge_mlp_mono<<<256, 512, 0, stream>>>(x, ei, b1, b2, gamma, beta, wbf,
                                           (float*)d_out, E);
  }
}

// Round 12
// 183.872 us; speedup vs baseline: 1.1225x; 1.0330x over previous
//
#include <hip/hip_runtime.h>

typedef unsigned short u16;
typedef unsigned int u32;
typedef __attribute__((ext_vector_type(8))) short bf16x8;
typedef __attribute__((ext_vector_type(4))) float f32x4;
typedef __attribute__((ext_vector_type(4))) u32 u32x4;

union U8 { u32 w[4]; u32x4 u4; bf16x8 v; };

#define LEAKY 0.2f
#define LN_EPS 1e-5f

// fp32 -> bf16 RTNE (bit math — proven; v_cvt_pk asm poisons words, round 6)
__device__ __forceinline__ u16 f2bf(float f) {
  union { float f; u32 u; } a; a.f = f;
  return (u16)((a.u + 0x7fffu + ((a.u >> 16) & 1u)) >> 16);
}
__device__ __forceinline__ u32 pk2(float lo, float hi) {
  return (u32)f2bf(lo) | ((u32)f2bf(hi) << 16);
}
// TRUNCATING bf16x2 pack in ONE v_perm_b32 (intermediates h1/h2 only; y and
// x->bf16 stay RTNE). Neutral perf (round 11) but harmless; keep.
__device__ __forceinline__ u32 pk2t(float lo, float hi) {
  return __builtin_amdgcn_perm(__float_as_uint(hi), __float_as_uint(lo),
                               0x07060302u);
}
__device__ __forceinline__ u32x4 pack8(const f32x4& a, const f32x4& b) {
  u32x4 r;
  r[0] = pk2(a[0], a[1]); r[1] = pk2(a[2], a[3]);
  r[2] = pk2(b[0], b[1]); r[3] = pk2(b[2], b[3]);
  return r;
}

// Build 128KB weight fragment image (128 frags x 1KB). frag f: lane l holds 8
// contiguous bf16 (one conflict-free ds_read_b128 at f*1024 + l*16).
// f = base + c*8 + n; W1: f 0..63 (c 0..3 = W1a/dest, c 4..7 = W1b/src);
// W2: f 64..95; W3: f 96..127.
// Element (f,l,i): p=l&15, q=l>>4, j=i&3, h=i>>2 -> W[16n+p][32c+4q+j+16h]
__global__ void build_wfrag(const float* __restrict__ W1,
                            const float* __restrict__ W2,
                            const float* __restrict__ W3,
                            u16* __restrict__ wout) {
  int id = blockIdx.x * 256 + threadIdx.x;     // 0..65535
  int f = id >> 9, l = (id >> 3) & 63, i = id & 7;
  int p = l & 15, q = l >> 4, j = i & 3, h = i >> 2;
  const float* W; int c, K;
  if (f < 64)      { W = W1; c = f >> 3;        K = 256; }
  else if (f < 96) { W = W2; c = (f - 64) >> 3; K = 128; }
  else             { W = W3; c = (f - 96) >> 3; K = 128; }
  int n = f & 7;
  wout[id] = f2bf(W[(16 * n + p) * K + 32 * c + 4 * q + j + 16 * h]);
}

// single-tile layer (M=16): frag f = FBASE + c*8 + n, one MFMA per frag read
template <int FBASE>
__device__ __forceinline__ void gemm16(const u16* __restrict__ wlds, int lane,
                                       const U8* mf, f32x4* acc) {
  #pragma unroll
  for (int c = 0; c < 4; ++c) {
    #pragma unroll
    for (int n = 0; n < 8; ++n) {
      U8 wf;
      wf.v = *(const bf16x8*)(wlds + ((FBASE + c * 8 + n) << 9) + (lane << 3));
      acc[n] = __builtin_amdgcn_mfma_f32_16x16x32_bf16(wf.v, mf[c].v, acc[n], 0, 0, 0);
    }
  }
}

// leaky (= max(v, 0.2v)) in place, then pack to next layer's bf16 frags
__device__ __forceinline__ void leaky_pack(f32x4* acc, U8* hf) {
  #pragma unroll
  for (int n = 0; n < 8; ++n) {
    #pragma unroll
    for (int j = 0; j < 4; ++j) {
      float v = acc[n][j];
      acc[n][j] = fmaxf(v, LEAKY * v);
    }
  }
  #pragma unroll
  for (int c = 0; c < 4; ++c) {
    hf[c].w[0] = pk2t(acc[2 * c][0],     acc[2 * c][1]);
    hf[c].w[1] = pk2t(acc[2 * c][2],     acc[2 * c][3]);
    hf[c].w[2] = pk2t(acc[2 * c + 1][0], acc[2 * c + 1][1]);
    hf[c].w[3] = pk2t(acc[2 * c + 1][2], acc[2 * c + 1][3]);
  }
}

// h1 frag word: leaky(bf16(ya)+bf16(yb)) on a packed pair (truncating pack)
__device__ __forceinline__ u32 addleaky(u32 ua, u32 ub) {
  float alo = __uint_as_float(ua << 16);
  float ahi = __uint_as_float(ua & 0xFFFF0000u);
  float blo = __uint_as_float(ub << 16);
  float bhi = __uint_as_float(ub & 0xFFFF0000u);
  float lo = alo + blo, hi = ahi + bhi;
  lo = fmaxf(lo, LEAKY * lo);
  hi = fmaxf(hi, LEAKY * hi);
  return pk2t(lo, hi);
}

// LayerNorm one 16-edge tile: acc[n][j] = h[edge p][chan 16n+4q+j].
// VECTOR f32x4 stores this round: one instruction writes a COMPLETE 64B line
// per row (4 lanes x 16B), 8 instrs/tile vs 32 scalar. Rounds 3-8's vector-
// store "amplification" was confounded (NT / spills / persistent scatter);
// this is the clean A/B on the round-9 schedule. Watch WRITE_SIZE: ~330MB
// expected; >450MB falsifies and we revert to scalar.
__device__ __forceinline__ void ln_store(const f32x4* acc, const f32x4* gmf,
                                         const f32x4* btf, int q,
                                         float* __restrict__ orow) {
  float s = 0.f, ss = 0.f;
  #pragma unroll
  for (int n = 0; n < 8; ++n) {
    #pragma unroll
    for (int j = 0; j < 4; ++j) { float v = acc[n][j]; s += v; ss += v * v; }
  }
  s += __shfl_xor(s, 16, 64);  ss += __shfl_xor(ss, 16, 64);
  s += __shfl_xor(s, 32, 64);  ss += __shfl_xor(ss, 32, 64);
  float mean = s * (1.f / 128.f);
  float var  = fmaxf(ss * (1.f / 128.f) - mean * mean, 0.f);
  float inv  = rsqrtf(var + LN_EPS);
  f32x4* o4 = (f32x4*)orow;
  #pragma unroll
  for (int n = 0; n < 8; ++n) {
    f32x4 gm = gmf[4 * n + q], bt = btf[4 * n + q];
    f32x4 r;
    r[0] = (acc[n][0] - mean) * inv * gm[0] + bt[0];
    r[1] = (acc[n][1] - mean) * inv * gm[1] + bt[1];
    r[2] = (acc[n][2] - mean) * inv * gm[2] + bt[2];
    r[3] = (acc[n][3] - mean) * inv * gm[3] + bt[3];
    o4[4 * n] = r;
  }
}

// ---- node precompute: y[n] = [ bf16(x[n]@W1a^T) | bf16(x[n]@W1b^T + b1) ]
// fragment order: elem (c, q, i=j+4h) at u16 offset c*32 + q*8 + i
// (RTNE kept here: y feeds every edge, keep its bias at zero.)
__global__ __launch_bounds__(512, 2) void node_pre(
    const float* __restrict__ x, const float* __restrict__ b1,
    const u16* __restrict__ wbf, u16* __restrict__ y, int NN) {
  __shared__ __align__(16) u16 wlds[32768];   // W1 frags (0..63), 64KB
  __shared__ __align__(16) float b1l[128];
  const int tid = threadIdx.x;
  {
    const uint4* s = (const uint4*)wbf;
    uint4* d = (uint4*)wlds;
    #pragma unroll
    for (int i = 0; i < 8; ++i) d[tid + i * 512] = s[tid + i * 512];
  }
  if (tid < 128) b1l[tid] = b1[tid];
  __syncthreads();

  const int lane = tid & 63, p = lane & 15, q = lane >> 4;
  const int wid = (blockIdx.x << 3) | (tid >> 6);
  const f32x4* b1f = (const f32x4*)b1l;
  const int NT = (NN + 15) >> 4;   // 16 nodes per wave-tile

  for (int t = wid; t < NT; t += 2048) {
    const int r = t * 16 + p;
    const int cr = r < NN ? r : NN - 1;
    U8 mf[4];
    #pragma unroll
    for (int c = 0; c < 4; ++c) {
      float4 a0 = *(const float4*)(x + (long)cr * 128 + 32 * c + 4 * q);
      float4 a1 = *(const float4*)(x + (long)cr * 128 + 32 * c + 4 * q + 16);
      mf[c].w[0] = pk2(a0.x, a0.y); mf[c].w[1] = pk2(a0.z, a0.w);
      mf[c].w[2] = pk2(a1.x, a1.y); mf[c].w[3] = pk2(a1.z, a1.w);
    }
    f32x4 ya[8], yb[8];
    #pragma unroll
    for (int n = 0; n < 8; ++n) {
      ya[n] = (f32x4)(0.f);
      yb[n] = b1f[4 * n + q];
    }
    gemm16<0>(wlds, lane, mf, ya);    // W1a (dest part)
    gemm16<32>(wlds, lane, mf, yb);   // W1b (src part, +b1)
    #pragma unroll
    for (int c = 0; c < 4; ++c) {
      *(u32x4*)(y + (long)r * 256 + c * 32 + q * 8)       = pack8(ya[2*c], ya[2*c+1]);
      *(u32x4*)(y + (long)r * 256 + 128 + c * 32 + q * 8) = pack8(yb[2*c], yb[2*c+1]);
    }
  }
}

// ---- edge kernel: EXACT round-9 schedule (measured best, 188us total).
// NON-persistent dispatch-order blocks; block = 512 contiguous edges; wave =
// 64 edges as 4 x 16-edge tiles, 2-deep ping-pong pipeline.
__global__ __launch_bounds__(512, 2) void edge_mlp_fac(
    const int* __restrict__ ei, const float* __restrict__ b2,
    const float* __restrict__ gamma, const float* __restrict__ beta,
    const u16* __restrict__ wbf, const u16* __restrict__ y,
    float* __restrict__ out, int E) {
  __shared__ __align__(16) u16 wlds[32768];   // W2|W3 frags, 64KB
  __shared__ __align__(16) float parl[384];   // b2 | gamma | beta
  const int tid = threadIdx.x;
  {
    const uint4* s = (const uint4*)wbf;
    uint4* d = (uint4*)wlds;
    #pragma unroll
    for (int i = 0; i < 8; ++i) d[tid + i * 512] = s[tid + i * 512];
  }
  if (tid < 384) {
    int prm = tid >> 7, idx = tid & 127;
    const float* src = (prm == 0) ? b2 : (prm == 1) ? gamma : beta;
    parl[tid] = src[idx];
  }
  __syncthreads();

  const int lane = tid & 63, p = lane & 15, q = lane >> 4;
  const f32x4* pf = (const f32x4*)parl;   // b2: pf[0..31], gm: +32, bt: +64
  const long ebase = (long)blockIdx.x * 512 + (tid >> 6) * 64;  // wave's 64 edges

  // all 4 tiles' indices up front
  int nd[4], ns[4];
  #pragma unroll
  for (int i = 0; i < 4; ++i) {
    nd[i] = ei[E + ebase + i * 16 + p];
    ns[i] = ei[ebase + i * 16 + p];
  }

#define LOADY(A, B, node_d, node_s)                                   \
  { const u16* yd_ = y + (long)(node_d) * 256;                        \
    const u16* ys_ = y + (long)(node_s) * 256 + 128;                  \
    _Pragma("unroll")                                                 \
    for (int c = 0; c < 4; ++c) {                                     \
      A[c] = *(const u32x4*)(yd_ + c * 32 + q * 8);                   \
      B[c] = *(const u32x4*)(ys_ + c * 32 + q * 8);                   \
    } }

  auto compute_store = [&](const u32x4* ya, const u32x4* yb, int i) {
    U8 hf[4];
    #pragma unroll
    for (int c = 0; c < 4; ++c) {
      #pragma unroll
      for (int w2 = 0; w2 < 4; ++w2) hf[c].w[w2] = addleaky(ya[c][w2], yb[c][w2]);
    }
    f32x4 acc[8];
    #pragma unroll
    for (int n = 0; n < 8; ++n) acc[n] = pf[4 * n + q];   // GEMM2 init = b2
    gemm16<0>(wlds, lane, hf, acc);
    leaky_pack(acc, hf);
    #pragma unroll
    for (int n = 0; n < 8; ++n) acc[n] = (f32x4)(0.f);    // GEMM3, no bias
    gemm16<32>(wlds, lane, hf, acc);
    ln_store(acc, pf + 32, pf + 64, q,
             out + (ebase + i * 16 + p) * 128 + 4 * q);
  };

  // explicit 2-deep ping-pong pipeline (static indexing only — rule #20)
  u32x4 a0[4], b0[4], a1[4], b1[4];
  LOADY(a0, b0, nd[0], ns[0]);
  LOADY(a1, b1, nd[1], ns[1]);
  compute_store(a0, b0, 0);
  LOADY(a0, b0, nd[2], ns[2]);
  compute_store(a1, b1, 1);
  LOADY(a1, b1, nd[3], ns[3]);
  compute_store(a0, b0, 2);
  compute_store(a1, b1, 3);
#undef LOADY
}

// ---- fallback (ws too small or E%512!=0): monolithic M=16 over x ----
__global__ __launch_bounds__(512, 2) void edge_mlp_mono(
    const float* __restrict__ x, const int* __restrict__ ei,
    const float* __restrict__ b1, const float* __restrict__ b2,
    const float* __restrict__ gamma, const float* __restrict__ beta,
    const u16* __restrict__ wbf, float* __restrict__ out, int E) {
  __shared__ __align__(16) u16 wlds[65536];
  __shared__ __align__(16) float parl[512];
  const int tid = threadIdx.x;
  {
    const uint4* s = (const uint4*)wbf;
    uint4* d = (uint4*)wlds;
    #pragma unroll
    for (int i = 0; i < 16; ++i) d[tid + i * 512] = s[tid + i * 512];
  }
  if (tid < 512) {
    int prm = tid >> 7, idx = tid & 127;
    const float* src = (prm == 0) ? b1 : (prm == 1) ? b2 : (prm == 2) ? gamma : beta;
    parl[tid] = src[idx];
  }
  __syncthreads();

  const int lane = tid & 63, p = lane & 15, q = lane >> 4;
  const int wid = (blockIdx.x << 3) | (tid >> 6);
  const f32x4* pf = (const f32x4*)parl;
  const int NT = (E + 15) >> 4;

  for (int t = wid; t < NT; t += 2048) {
    const int e0 = t * 16;
    const int e = (e0 + p < E) ? e0 + p : E - 1;
    const int nd = ei[E + e], ns = ei[e];
    U8 mf[4];
    f32x4 acc[8];
    #pragma unroll
    for (int n = 0; n < 8; ++n) acc[n] = pf[4 * n + q];
    #pragma unroll
    for (int c = 0; c < 4; ++c) {
      float4 a0 = *(const float4*)(x + (long)nd * 128 + 32 * c + 4 * q);
      float4 a1 = *(const float4*)(x + (long)nd * 128 + 32 * c + 4 * q + 16);
      mf[c].w[0] = pk2(a0.x, a0.y); mf[c].w[1] = pk2(a0.z, a0.w);
      mf[c].w[2] = pk2(a1.x, a1.y); mf[c].w[3] = pk2(a1.z, a1.w);
    }
    gemm16<0>(wlds, lane, mf, acc);
    #pragma unroll
    for (int c = 0; c < 4; ++c) {
      float4 a0 = *(const float4*)(x + (long)ns * 128 + 32 * c + 4 * q);
      float4 a1 = *(const float4*)(x + (long)ns * 128 + 32 * c + 4 * q + 16);
      mf[c].w[0] = pk2(a0.x, a0.y); mf[c].w[1] = pk2(a0.z, a0.w);
      mf[c].w[2] = pk2(a1.x, a1.y); mf[c].w[3] = pk2(a1.z, a1.w);
    }
    gemm16<32>(wlds, lane, mf, acc);
    U8 hf[4];
    leaky_pack(acc, hf);
    #pragma unroll
    for (int n = 0; n < 8; ++n) acc[n] = pf[32 + 4 * n + q];
    gemm16<64>(wlds, lane, hf, acc);
    leaky_pack(acc, hf);
    #pragma unroll
    for (int n = 0; n < 8; ++n) acc[n] = (f32x4)(0.f);
    gemm16<96>(wlds, lane, hf, acc);
    if (e0 + p < E)
      ln_store(acc, pf + 64, pf + 96, q, out + (long)(e0 + p) * 128 + 4 * q);
  }
}

extern "C" void kernel_launch(void* const* d_in, const int* in_sizes, int n_in,
                              void* d_out, int out_size, void* d_ws, size_t ws_size,
                              hipStream_t stream) {
  const float* x     = (const float*)d_in[0];
  const int*   ei    = (const int*)d_in[1];
  const float* W1    = (const float*)d_in[2];
  const float* b1    = (const float*)d_in[3];
  const float* W2    = (const float*)d_in[4];
  const float* b2    = (const float*)d_in[5];
  const float* W3    = (const float*)d_in[6];
  const float* gamma = (const float*)d_in[7];
  const float* beta  = (const float*)d_in[8];
  const int E  = in_sizes[1] / 2;     // 640000
  const int NN = in_sizes[0] / 128;   // 50000

  const size_t npad    = ((size_t)(NN + 31) / 32) * 32;
  const size_t Y_BYTES = npad * 512;             // bf16 ya|yb per node
  const size_t NEED    = Y_BYTES + 131072;

  if (ws_size >= NEED && (E % 512) == 0) {
    u16* y   = (u16*)d_ws;
    u16* wbf = (u16*)((char*)d_ws + Y_BYTES);
    build_wfrag<<<256, 256, 0, stream>>>(W1, W2, W3, wbf);
    node_pre<<<256, 512, 0, stream>>>(x, b1, wbf, y, NN);
    edge_mlp_fac<<<E / 512, 512, 0, stream>>>(ei, b2, gamma, beta, wbf + 32768,
                                              y, (float*)d_out, E);
  } else {
    u16* wbf = (u16*)d_ws;
    build_wfrag<<<256, 256, 0, stream>>>(W1, W2, W3, wbf);
    edge_mlp_mono<<<256, 512, 0, stream>>>(x, ei, b1, b2, gamma, beta, wbf,
                                           (float*)d_out, E);
  }
}

// Round 13
// 162.771 us; speedup vs baseline: 1.2680x; 1.1296x over previous
//
#include <hip/hip_runtime.h>

typedef unsigned short u16;
typedef unsigned int u32;
typedef __attribute__((ext_vector_type(8))) short bf16x8;
typedef __attribute__((ext_vector_type(4))) float f32x4;
typedef __attribute__((ext_vector_type(4))) u32 u32x4;

union U8 { u32 w[4]; u32x4 u4; bf16x8 v; };

#define LEAKY 0.2f
#define LN_EPS 1e-5f

// fp32 -> bf16 RTNE (bit math — proven; v_cvt_pk asm poisons words, round 6)
__device__ __forceinline__ u16 f2bf(float f) {
  union { float f; u32 u; } a; a.f = f;
  return (u16)((a.u + 0x7fffu + ((a.u >> 16) & 1u)) >> 16);
}
__device__ __forceinline__ u32 pk2(float lo, float hi) {
  return (u32)f2bf(lo) | ((u32)f2bf(hi) << 16);
}
// TRUNCATING bf16x2 pack in ONE v_perm_b32 (intermediates h1/h2 only)
__device__ __forceinline__ u32 pk2t(float lo, float hi) {
  return __builtin_amdgcn_perm(__float_as_uint(hi), __float_as_uint(lo),
                               0x07060302u);
}
__device__ __forceinline__ u32x4 pack8(const f32x4& a, const f32x4& b) {
  u32x4 r;
  r[0] = pk2(a[0], a[1]); r[1] = pk2(a[2], a[3]);
  r[2] = pk2(b[0], b[1]); r[3] = pk2(b[2], b[3]);
  return r;
}

// Build 128KB weight fragment image (128 frags x 1KB). frag f: lane l holds 8
// contiguous bf16 (one conflict-free ds_read_b128 at f*1024 + l*16).
// f = base + c*8 + n; W1: f 0..63 (c 0..3 = W1a/dest, c 4..7 = W1b/src);
// W2: f 64..95; W3: f 96..127.
// Element (f,l,i): p=l&15, q=l>>4, j=i&3, h=i>>2 -> W[16n+p][32c+4q+j+16h]
__global__ void build_wfrag(const float* __restrict__ W1,
                            const float* __restrict__ W2,
                            const float* __restrict__ W3,
                            u16* __restrict__ wout) {
  int id = blockIdx.x * 256 + threadIdx.x;     // 0..65535
  int f = id >> 9, l = (id >> 3) & 63, i = id & 7;
  int p = l & 15, q = l >> 4, j = i & 3, h = i >> 2;
  const float* W; int c, K;
  if (f < 64)      { W = W1; c = f >> 3;        K = 256; }
  else if (f < 96) { W = W2; c = (f - 64) >> 3; K = 128; }
  else             { W = W3; c = (f - 96) >> 3; K = 128; }
  int n = f & 7;
  wout[id] = f2bf(W[(16 * n + p) * K + 32 * c + 4 * q + j + 16 * h]);
}

// single-tile layer (M=16): frag f = FBASE + c*8 + n, one MFMA per frag read
template <int FBASE>
__device__ __forceinline__ void gemm16(const u16* __restrict__ wlds, int lane,
                                       const U8* mf, f32x4* acc) {
  #pragma unroll
  for (int c = 0; c < 4; ++c) {
    #pragma unroll
    for (int n = 0; n < 8; ++n) {
      U8 wf;
      wf.v = *(const bf16x8*)(wlds + ((FBASE + c * 8 + n) << 9) + (lane << 3));
      acc[n] = __builtin_amdgcn_mfma_f32_16x16x32_bf16(wf.v, mf[c].v, acc[n], 0, 0, 0);
    }
  }
}

// leaky (= max(v, 0.2v)) in place, then pack to next layer's bf16 frags
__device__ __forceinline__ void leaky_pack(f32x4* acc, U8* hf) {
  #pragma unroll
  for (int n = 0; n < 8; ++n) {
    #pragma unroll
    for (int j = 0; j < 4; ++j) {
      float v = acc[n][j];
      acc[n][j] = fmaxf(v, LEAKY * v);
    }
  }
  #pragma unroll
  for (int c = 0; c < 4; ++c) {
    hf[c].w[0] = pk2t(acc[2 * c][0],     acc[2 * c][1]);
    hf[c].w[1] = pk2t(acc[2 * c][2],     acc[2 * c][3]);
    hf[c].w[2] = pk2t(acc[2 * c + 1][0], acc[2 * c + 1][1]);
    hf[c].w[3] = pk2t(acc[2 * c + 1][2], acc[2 * c + 1][3]);
  }
}

// h1 frag word: leaky(bf16(ya)+bf16(yb)) on a packed pair (truncating pack)
__device__ __forceinline__ u32 addleaky(u32 ua, u32 ub) {
  float alo = __uint_as_float(ua << 16);
  float ahi = __uint_as_float(ua & 0xFFFF0000u);
  float blo = __uint_as_float(ub << 16);
  float bhi = __uint_as_float(ub & 0xFFFF0000u);
  float lo = alo + blo, hi = ahi + bhi;
  lo = fmaxf(lo, LEAKY * lo);
  hi = fmaxf(hi, LEAKY * hi);
  return pk2t(lo, hi);
}

// LayerNorm one 16-edge tile: acc[n][j] = h[edge p][chan 16n+4q+j].
// Vector f32x4 full-line stores (round-12 win), now NONTEMPORAL: the output
// stream is written once, never re-read — keep it out of L2/L3 so the y
// gather's 25.6MB hot set stays resident (round-8 FETCH=970MB showed the
// gather was running reuse-free; write-stream thrash is the prime suspect).
// Round 3's NT amplification was confounded (persistent scattered writes);
// this is the clean A/B. If dur regresses >210us, revert NT.
__device__ __forceinline__ void ln_store(const f32x4* acc, const f32x4* gmf,
                                         const f32x4* btf, int q,
                                         float* __restrict__ orow) {
  float s = 0.f, ss = 0.f;
  #pragma unroll
  for (int n = 0; n < 8; ++n) {
    #pragma unroll
    for (int j = 0; j < 4; ++j) { float v = acc[n][j]; s += v; ss += v * v; }
  }
  s += __shfl_xor(s, 16, 64);  ss += __shfl_xor(ss, 16, 64);
  s += __shfl_xor(s, 32, 64);  ss += __shfl_xor(ss, 32, 64);
  float mean = s * (1.f / 128.f);
  float var  = fmaxf(ss * (1.f / 128.f) - mean * mean, 0.f);
  float inv  = rsqrtf(var + LN_EPS);
  f32x4* o4 = (f32x4*)orow;
  #pragma unroll
  for (int n = 0; n < 8; ++n) {
    f32x4 gm = gmf[4 * n + q], bt = btf[4 * n + q];
    f32x4 r;
    r[0] = (acc[n][0] - mean) * inv * gm[0] + bt[0];
    r[1] = (acc[n][1] - mean) * inv * gm[1] + bt[1];
    r[2] = (acc[n][2] - mean) * inv * gm[2] + bt[2];
    r[3] = (acc[n][3] - mean) * inv * gm[3] + bt[3];
    __builtin_nontemporal_store(r, o4 + 4 * n);
  }
}

// ---- node precompute: y[n] = [ bf16(x[n]@W1a^T) | bf16(x[n]@W1b^T + b1) ]
// fragment order: elem (c, q, i=j+4h) at u16 offset c*32 + q*8 + i
// (RTNE kept here: y feeds every edge. y is RE-READ — normal stores.)
__global__ __launch_bounds__(512, 2) void node_pre(
    const float* __restrict__ x, const float* __restrict__ b1,
    const u16* __restrict__ wbf, u16* __restrict__ y, int NN) {
  __shared__ __align__(16) u16 wlds[32768];   // W1 frags (0..63), 64KB
  __shared__ __align__(16) float b1l[128];
  const int tid = threadIdx.x;
  {
    const uint4* s = (const uint4*)wbf;
    uint4* d = (uint4*)wlds;
    #pragma unroll
    for (int i = 0; i < 8; ++i) d[tid + i * 512] = s[tid + i * 512];
  }
  if (tid < 128) b1l[tid] = b1[tid];
  __syncthreads();

  const int lane = tid & 63, p = lane & 15, q = lane >> 4;
  const int wid = (blockIdx.x << 3) | (tid >> 6);
  const f32x4* b1f = (const f32x4*)b1l;
  const int NT = (NN + 15) >> 4;   // 16 nodes per wave-tile

  for (int t = wid; t < NT; t += 2048) {
    const int r = t * 16 + p;
    const int cr = r < NN ? r : NN - 1;
    U8 mf[4];
    #pragma unroll
    for (int c = 0; c < 4; ++c) {
      float4 a0 = *(const float4*)(x + (long)cr * 128 + 32 * c + 4 * q);
      float4 a1 = *(const float4*)(x + (long)cr * 128 + 32 * c + 4 * q + 16);
      mf[c].w[0] = pk2(a0.x, a0.y); mf[c].w[1] = pk2(a0.z, a0.w);
      mf[c].w[2] = pk2(a1.x, a1.y); mf[c].w[3] = pk2(a1.z, a1.w);
    }
    f32x4 ya[8], yb[8];
    #pragma unroll
    for (int n = 0; n < 8; ++n) {
      ya[n] = (f32x4)(0.f);
      yb[n] = b1f[4 * n + q];
    }
    gemm16<0>(wlds, lane, mf, ya);    // W1a (dest part)
    gemm16<32>(wlds, lane, mf, yb);   // W1b (src part, +b1)
    #pragma unroll
    for (int c = 0; c < 4; ++c) {
      *(u32x4*)(y + (long)r * 256 + c * 32 + q * 8)       = pack8(ya[2*c], ya[2*c+1]);
      *(u32x4*)(y + (long)r * 256 + 128 + c * 32 + q * 8) = pack8(yb[2*c], yb[2*c+1]);
    }
  }
}

// ---- edge kernel: EXACT round-9 schedule (measured best).
// NON-persistent dispatch-order blocks; block = 512 contiguous edges; wave =
// 64 edges as 4 x 16-edge tiles, 2-deep ping-pong pipeline.
__global__ __launch_bounds__(512, 2) void edge_mlp_fac(
    const int* __restrict__ ei, const float* __restrict__ b2,
    const float* __restrict__ gamma, const float* __restrict__ beta,
    const u16* __restrict__ wbf, const u16* __restrict__ y,
    float* __restrict__ out, int E) {
  __shared__ __align__(16) u16 wlds[32768];   // W2|W3 frags, 64KB
  __shared__ __align__(16) float parl[384];   // b2 | gamma | beta
  const int tid = threadIdx.x;
  {
    const uint4* s = (const uint4*)wbf;
    uint4* d = (uint4*)wlds;
    #pragma unroll
    for (int i = 0; i < 8; ++i) d[tid + i * 512] = s[tid + i * 512];
  }
  if (tid < 384) {
    int prm = tid >> 7, idx = tid & 127;
    const float* src = (prm == 0) ? b2 : (prm == 1) ? gamma : beta;
    parl[tid] = src[idx];
  }
  __syncthreads();

  const int lane = tid & 63, p = lane & 15, q = lane >> 4;
  const f32x4* pf = (const f32x4*)parl;   // b2: pf[0..31], gm: +32, bt: +64
  const long ebase = (long)blockIdx.x * 512 + (tid >> 6) * 64;  // wave's 64 edges

  // all 4 tiles' indices up front
  int nd[4], ns[4];
  #pragma unroll
  for (int i = 0; i < 4; ++i) {
    nd[i] = ei[E + ebase + i * 16 + p];
    ns[i] = ei[ebase + i * 16 + p];
  }

#define LOADY(A, B, node_d, node_s)                                   \
  { const u16* yd_ = y + (long)(node_d) * 256;                        \
    const u16* ys_ = y + (long)(node_s) * 256 + 128;                  \
    _Pragma("unroll")                                                 \
    for (int c = 0; c < 4; ++c) {                                     \
      A[c] = *(const u32x4*)(yd_ + c * 32 + q * 8);                   \
      B[c] = *(const u32x4*)(ys_ + c * 32 + q * 8);                   \
    } }

  auto compute_store = [&](const u32x4* ya, const u32x4* yb, int i) {
    U8 hf[4];
    #pragma unroll
    for (int c = 0; c < 4; ++c) {
      #pragma unroll
      for (int w2 = 0; w2 < 4; ++w2) hf[c].w[w2] = addleaky(ya[c][w2], yb[c][w2]);
    }
    f32x4 acc[8];
    #pragma unroll
    for (int n = 0; n < 8; ++n) acc[n] = pf[4 * n + q];   // GEMM2 init = b2
    gemm16<0>(wlds, lane, hf, acc);
    leaky_pack(acc, hf);
    #pragma unroll
    for (int n = 0; n < 8; ++n) acc[n] = (f32x4)(0.f);    // GEMM3, no bias
    gemm16<32>(wlds, lane, hf, acc);
    ln_store(acc, pf + 32, pf + 64, q,
             out + (ebase + i * 16 + p) * 128 + 4 * q);
  };

  // explicit 2-deep ping-pong pipeline (static indexing only — rule #20)
  u32x4 a0[4], b0[4], a1[4], b1[4];
  LOADY(a0, b0, nd[0], ns[0]);
  LOADY(a1, b1, nd[1], ns[1]);
  compute_store(a0, b0, 0);
  LOADY(a0, b0, nd[2], ns[2]);
  compute_store(a1, b1, 1);
  LOADY(a1, b1, nd[3], ns[3]);
  compute_store(a0, b0, 2);
  compute_store(a1, b1, 3);
#undef LOADY
}

// ---- fallback (ws too small or E%512!=0): monolithic M=16 over x ----
__global__ __launch_bounds__(512, 2) void edge_mlp_mono(
    const float* __restrict__ x, const int* __restrict__ ei,
    const float* __restrict__ b1, const float* __restrict__ b2,
    const float* __restrict__ gamma, const float* __restrict__ beta,
    const u16* __restrict__ wbf, float* __restrict__ out, int E) {
  __shared__ __align__(16) u16 wlds[65536];
  __shared__ __align__(16) float parl[512];
  const int tid = threadIdx.x;
  {
    const uint4* s = (const uint4*)wbf;
    uint4* d = (uint4*)wlds;
    #pragma unroll
    for (int i = 0; i < 16; ++i) d[tid + i * 512] = s[tid + i * 512];
  }
  if (tid < 512) {
    int prm = tid >> 7, idx = tid & 127;
    const float* src = (prm == 0) ? b1 : (prm == 1) ? b2 : (prm == 2) ? gamma : beta;
    parl[tid] = src[idx];
  }
  __syncthreads();

  const int lane = tid & 63, p = lane & 15, q = lane >> 4;
  const int wid = (blockIdx.x << 3) | (tid >> 6);
  const f32x4* pf = (const f32x4*)parl;
  const int NT = (E + 15) >> 4;

  for (int t = wid; t < NT; t += 2048) {
    const int e0 = t * 16;
    const int e = (e0 + p < E) ? e0 + p : E - 1;
    const int nd = ei[E + e], ns = ei[e];
    U8 mf[4];
    f32x4 acc[8];
    #pragma unroll
    for (int n = 0; n < 8; ++n) acc[n] = pf[4 * n + q];
    #pragma unroll
    for (int c = 0; c < 4; ++c) {
      float4 a0 = *(const float4*)(x + (long)nd * 128 + 32 * c + 4 * q);
      float4 a1 = *(const float4*)(x + (long)nd * 128 + 32 * c + 4 * q + 16);
      mf[c].w[0] = pk2(a0.x, a0.y); mf[c].w[1] = pk2(a0.z, a0.w);
      mf[c].w[2] = pk2(a1.x, a1.y); mf[c].w[3] = pk2(a1.z, a1.w);
    }
    gemm16<0>(wlds, lane, mf, acc);
    #pragma unroll
    for (int c = 0; c < 4; ++c) {
      float4 a0 = *(const float4*)(x + (long)ns * 128 + 32 * c + 4 * q);
      float4 a1 = *(const float4*)(x + (long)ns * 128 + 32 * c + 4 * q + 16);
      mf[c].w[0] = pk2(a0.x, a0.y); mf[c].w[1] = pk2(a0.z, a0.w);
      mf[c].w[2] = pk2(a1.x, a1.y); mf[c].w[3] = pk2(a1.z, a1.w);
    }
    gemm16<32>(wlds, lane, mf, acc);
    U8 hf[4];
    leaky_pack(acc, hf);
    #pragma unroll
    for (int n = 0; n < 8; ++n) acc[n] = pf[32 + 4 * n + q];
    gemm16<64>(wlds, lane, hf, acc);
    leaky_pack(acc, hf);
    #pragma unroll
    for (int n = 0; n < 8; ++n) acc[n] = (f32x4)(0.f);
    gemm16<96>(wlds, lane, hf, acc);
    if (e0 + p < E)
      ln_store(acc, pf + 64, pf + 96, q, out + (long)(e0 + p) * 128 + 4 * q);
  }
}

extern "C" void kernel_launch(void* const* d_in, const int* in_sizes, int n_in,
                              void* d_out, int out_size, void* d_ws, size_t ws_size,
                              hipStream_t stream) {
  const float* x     = (const float*)d_in[0];
  const int*   ei    = (const int*)d_in[1];
  const float* W1    = (const float*)d_in[2];
  const float* b1    = (const float*)d_in[3];
  const float* W2    = (const float*)d_in[4];
  const float* b2    = (const float*)d_in[5];
  const float* W3    = (const float*)d_in[6];
  const float* gamma = (const float*)d_in[7];
  const float* beta  = (const float*)d_in[8];
  const int E  = in_sizes[1] / 2;     // 640000
  const int NN = in_sizes[0] / 128;   // 50000

  const size_t npad    = ((size_t)(NN + 31) / 32) * 32;
  const size_t Y_BYTES = npad * 512;             // bf16 ya|yb per node
  const size_t NEED    = Y_BYTES + 131072;

  if (ws_size >= NEED && (E % 512) == 0) {
    u16* y   = (u16*)d_ws;
    u16* wbf = (u16*)((char*)d_ws + Y_BYTES);
    build_wfrag<<<256, 256, 0, stream>>>(W1, W2, W3, wbf);
    node_pre<<<256, 512, 0, stream>>>(x, b1, wbf, y, NN);
    edge_mlp_fac<<<E / 512, 512, 0, stream>>>(ei, b2, gamma, beta, wbf + 32768,
                                              y, (float*)d_out, E);
  } else {
    u16* wbf = (u16*)d_ws;
    build_wfrag<<<256, 256, 0, stream>>>(W1, W2, W3, wbf);
    edge_mlp_mono<<<256, 512, 0, stream>>>(x, ei, b1, b2, gamma, beta, wbf,
                                           (float*)d_out, E);
  }
}